// Round 1
// baseline (209.035 us; speedup 1.0000x reference)
//
#include <hip/hip_runtime.h>

// SplineConv: out[n, o, i] = sum_{a,b in 0..2} wx[n,a]*wy[n,b] * C[o,i,kx-2+a,ky-2+b]
// N=32768 points, C is (32,32,7,7) f32, out is (N,32,32) f32 = 128 MiB (HBM-write-bound).

#define NPTS   32768
#define NH     7
#define NW     7
#define DIM    1024        // 32*32 channels
#define PPB    128         // points per main-kernel block
#define OIGRP  4           // 4 groups of 256 channels

__device__ __forceinline__ float safe_div(float n, float d) {
    // matches reference _safe_div: den==0 -> num/1 = num
    return (d == 0.0f) ? n : (n / d);
}

__device__ __forceinline__ void span_weights(float v, const float* __restrict__ T,
                                             int& k, float& w0, float& w1, float& w2) {
    // searchsorted(T, v, 'right')-1 for T = [lo,lo,lo, t3,t4,t5,t6, hi,hi,hi]
    float t3 = T[3], t4 = T[4], t5 = T[5], t6 = T[6];
    k = 2 + (v >= t3) + (v >= t4) + (v >= t5) + (v >= t6);
    float Tm1 = T[k - 1], T0 = T[k], Tp1 = T[k + 1], Tp2 = T[k + 2];
    // de Boor (order 2) collapsed to basis weights:
    float a10 = safe_div(v - Tm1, Tp1 - Tm1);
    float a11 = safe_div(v - T0,  Tp2 - T0);
    float a21 = safe_div(v - T0,  Tp1 - T0);
    w0 = (1.0f - a21) * (1.0f - a10);
    w1 = (1.0f - a21) * a10 + a21 * (1.0f - a11);
    w2 = a21 * a11;
}

__global__ void precompute_kernel(const float* __restrict__ xy,
                                  const float* __restrict__ Tx,
                                  const float* __restrict__ Ty,
                                  int* __restrict__ offs,
                                  float* __restrict__ wts) {
    int n = blockIdx.x * blockDim.x + threadIdx.x;
    if (n >= NPTS) return;
    float x = xy[2 * n + 0];
    float y = xy[2 * n + 1];

    int kx, ky;
    float wx0, wx1, wx2, wy0, wy1, wy2;
    span_weights(x, Tx, kx, wx0, wx1, wx2);
    span_weights(y, Ty, ky, wy0, wy1, wy2);

    offs[n] = (kx - 2) * 7 + (ky - 2);
    float* r = wts + n * 12;           // 12-dword record, 16B-aligned
    r[0] = wx0 * wy0;  r[1] = wx0 * wy1;  r[2] = wx0 * wy2;
    r[3] = wx1 * wy0;  r[4] = wx1 * wy1;  r[5] = wx1 * wy2;
    r[6] = wx2 * wy0;  r[7] = wx2 * wy1;  r[8] = wx2 * wy2;
    r[9] = 0.0f; r[10] = 0.0f; r[11] = 0.0f;
}

__global__ __launch_bounds__(256) void spline_main_kernel(
    const float* __restrict__ C,
    const int* __restrict__ offs,
    const float* __restrict__ wts,
    float* __restrict__ out)
{
    __shared__ float lds[256 * 49];
    const int t      = threadIdx.x;
    const int g      = blockIdx.x & (OIGRP - 1);
    const int chunk  = blockIdx.x >> 2;
    const int oibase = g * 256;

    // Stage this group's 256 channel rows (256*49 f32 = 50176 B) into LDS, coalesced.
    {
        const float4* src = (const float4*)(C + (size_t)oibase * 49);
        float4* dst = (float4*)lds;
        for (int i = t; i < (256 * 49) / 4; i += 256) dst[i] = src[i];
    }
    __syncthreads();

    // Unpack my channel's 7x7 coefficients to registers (stride 49: 2-way bank alias = free).
    float c[49];
#pragma unroll
    for (int q = 0; q < 49; ++q) c[q] = lds[t * 49 + q];

    const int p0 = chunk * PPB;
    float* outp = out + (size_t)p0 * DIM + oibase + t;

    for (int p = p0; p < p0 + PPB; ++p) {
        // Block-uniform loads -> scalar path (s_load), weights land in SGPRs.
        const int off = offs[p];
        const float* r = wts + p * 12;
        const float w0 = r[0], w1 = r[1], w2 = r[2];
        const float w3 = r[3], w4 = r[4], w5 = r[5];
        const float w6 = r[6], w7 = r[7], w8 = r[8];

        float s;
        // Uniform 25-way switch: compile-time register indices into c[] (no scratch).
        switch (off) {
#define CASE_IJ(i, j)                                              \
        case ((i) * 7 + (j)):                                      \
            s = w0 * c[(i) * 7 + (j)];                             \
            s = fmaf(w1, c[(i) * 7 + (j) + 1], s);                 \
            s = fmaf(w2, c[(i) * 7 + (j) + 2], s);                 \
            s = fmaf(w3, c[((i) + 1) * 7 + (j)], s);               \
            s = fmaf(w4, c[((i) + 1) * 7 + (j) + 1], s);           \
            s = fmaf(w5, c[((i) + 1) * 7 + (j) + 2], s);           \
            s = fmaf(w6, c[((i) + 2) * 7 + (j)], s);               \
            s = fmaf(w7, c[((i) + 2) * 7 + (j) + 1], s);           \
            s = fmaf(w8, c[((i) + 2) * 7 + (j) + 2], s);           \
            break;
        CASE_IJ(0, 0) CASE_IJ(0, 1) CASE_IJ(0, 2) CASE_IJ(0, 3) CASE_IJ(0, 4)
        CASE_IJ(1, 0) CASE_IJ(1, 1) CASE_IJ(1, 2) CASE_IJ(1, 3) CASE_IJ(1, 4)
        CASE_IJ(2, 0) CASE_IJ(2, 1) CASE_IJ(2, 2) CASE_IJ(2, 3) CASE_IJ(2, 4)
        CASE_IJ(3, 0) CASE_IJ(3, 1) CASE_IJ(3, 2) CASE_IJ(3, 3) CASE_IJ(3, 4)
        CASE_IJ(4, 0) CASE_IJ(4, 1) CASE_IJ(4, 2) CASE_IJ(4, 3) CASE_IJ(4, 4)
#undef CASE_IJ
        default: s = 0.0f; break;
        }

        *outp = s;          // coalesced: lane t writes 4B at (oibase + t)
        outp += DIM;
    }
}

extern "C" void kernel_launch(void* const* d_in, const int* in_sizes, int n_in,
                              void* d_out, int out_size, void* d_ws, size_t ws_size,
                              hipStream_t stream) {
    const float* xy = (const float*)d_in[0];
    const float* Tx = (const float*)d_in[1];
    const float* Ty = (const float*)d_in[2];
    const float* C  = (const float*)d_in[3];
    float* out = (float*)d_out;

    int*   offs = (int*)d_ws;                    // 32768 ints
    float* wts  = (float*)d_ws + NPTS;           // 32768 x 12 floats (16B-aligned records)

    precompute_kernel<<<NPTS / 256, 256, 0, stream>>>(xy, Tx, Ty, offs, wts);
    spline_main_kernel<<<OIGRP * (NPTS / PPB), 256, 0, stream>>>(C, offs, wts, out);
}

// Round 4
// 45.304 us; speedup vs baseline: 4.6141x; 4.6141x over previous
//
#include <hip/hip_runtime.h>

// SplineConv: out[n, o, i] = sum_{a,b in 0..2} wx[n,a]*wy[n,b] * C[o,i,kx-2+a,ky-2+b]
// N=32768 points, C is (32,32,7,7) f32, out is (N,32,32) f32 = 128 MiB (HBM-write-bound).
//
// Structure: per-point weights/offset precomputed (kernel 1). Main kernel:
// each thread owns TWO channels; their 2x49 coefficients live in registers,
// PLANAR layout (c[0..48] = row ch, c[49..97] = row ch+1), all indices
// compile-time. The window offset is READFIRSTLANE'd to an SGPR so the 25-way
// switch compiles to a scalar jump table (a vector switch gets if-converted
// into ~500 predicated VALU ops/point). Weights prefetched one point ahead.

#define NPTS   32768
#define DIM    1024        // 32*32 channels
#define PPB    64          // points per main-kernel block
#define WREC   12          // dwords per weight record (16B aligned)

__device__ __forceinline__ float safe_div(float n, float d) {
    return (d == 0.0f) ? n : (n / d);
}

__device__ __forceinline__ void span_weights(float v, const float* __restrict__ T,
                                             int& k, float& w0, float& w1, float& w2) {
    float t3 = T[3], t4 = T[4], t5 = T[5], t6 = T[6];
    k = 2 + (v >= t3) + (v >= t4) + (v >= t5) + (v >= t6);
    float Tm1 = T[k - 1], T0 = T[k], Tp1 = T[k + 1], Tp2 = T[k + 2];
    float a10 = safe_div(v - Tm1, Tp1 - Tm1);
    float a11 = safe_div(v - T0,  Tp2 - T0);
    float a21 = safe_div(v - T0,  Tp1 - T0);
    w0 = (1.0f - a21) * (1.0f - a10);
    w1 = (1.0f - a21) * a10 + a21 * (1.0f - a11);
    w2 = a21 * a11;
}

__global__ void precompute_kernel(const float* __restrict__ xy,
                                  const float* __restrict__ Tx,
                                  const float* __restrict__ Ty,
                                  int* __restrict__ offs,
                                  float* __restrict__ wts) {
    int n = blockIdx.x * blockDim.x + threadIdx.x;
    if (n >= NPTS) return;
    float x = xy[2 * n + 0];
    float y = xy[2 * n + 1];

    int kx, ky;
    float wx0, wx1, wx2, wy0, wy1, wy2;
    span_weights(x, Tx, kx, wx0, wx1, wx2);
    span_weights(y, Ty, ky, wy0, wy1, wy2);

    offs[n] = (kx - 2) * 7 + (ky - 2);
    float* r = wts + n * WREC;
    r[0] = wx0 * wy0;  r[1] = wx0 * wy1;  r[2] = wx0 * wy2;
    r[3] = wx1 * wy0;  r[4] = wx1 * wy1;  r[5] = wx1 * wy2;
    r[6] = wx2 * wy0;  r[7] = wx2 * wy1;  r[8] = wx2 * wy2;
    r[9] = 0.0f; r[10] = 0.0f; r[11] = 0.0f;
}

__global__ __launch_bounds__(256) void spline_main_kernel(
    const float* __restrict__ C,
    const int* __restrict__ offs,
    const float* __restrict__ wts,
    float* __restrict__ out)
{
    const int t     = threadIdx.x;
    const int g     = blockIdx.x & 1;          // channel half: 0 or 1
    const int chunk = blockIdx.x >> 1;
    const int ch    = g * 512 + t * 2;         // this thread's first channel

    // Two channel rows -> registers, PLANAR: c[0..48] = row ch, c[49..97] = row ch+1.
    // ch is even -> (C + ch*49) is 8B-aligned -> float2 loads are legal.
    float c[98];
    {
        const float2* src = (const float2*)(C + (size_t)ch * 49);
#pragma unroll
        for (int q = 0; q < 49; ++q) {
            float2 v = src[q];
            c[2 * q]     = v.x;     // linear fill: c[i] = C[ch*49 + i]
            c[2 * q + 1] = v.y;
        }
    }

    const int p0   = chunk * PPB;
    const int pend = p0 + PPB;
    float2* outp = (float2*)(out + (size_t)p0 * DIM + ch);

    // Prefetch first point's record (uniform address -> one cache line per wave).
    int    off_n = offs[p0];
    float4 wAn = *(const float4*)(wts + (size_t)p0 * WREC);
    float4 wBn = *(const float4*)(wts + (size_t)p0 * WREC + 4);
    float  w8n = wts[(size_t)p0 * WREC + 8];

    for (int p = p0; p < pend; ++p) {
        const int off = __builtin_amdgcn_readfirstlane(off_n);  // SGPR -> scalar switch
        const float w0 = wAn.x, w1 = wAn.y, w2 = wAn.z, w3 = wAn.w;
        const float w4 = wBn.x, w5 = wBn.y, w6 = wBn.z, w7 = wBn.w;
        const float w8 = w8n;

        if (p + 1 < pend) {   // software prefetch next record under this point's FMAs
            off_n = offs[p + 1];
            wAn = *(const float4*)(wts + (size_t)(p + 1) * WREC);
            wBn = *(const float4*)(wts + (size_t)(p + 1) * WREC + 4);
            w8n = wts[(size_t)(p + 1) * WREC + 8];
        }

        float s0, s1;
        switch (off) {
#define TERM(q, dq, w)                                      \
            s0 = fmaf(w, c[(q) + (dq)],      s0);           \
            s1 = fmaf(w, c[49 + (q) + (dq)], s1);
#define CASE_IJ(i, j)                                       \
        case ((i) * 7 + (j)): {                             \
            const int q = (i) * 7 + (j);                    \
            s0 = w0 * c[q];                                 \
            s1 = w0 * c[49 + q];                            \
            TERM(q, 1,  w1)  TERM(q, 2,  w2)                \
            TERM(q, 7,  w3)  TERM(q, 8,  w4)  TERM(q, 9,  w5) \
            TERM(q, 14, w6)  TERM(q, 15, w7)  TERM(q, 16, w8) \
        } break;
        CASE_IJ(0, 0) CASE_IJ(0, 1) CASE_IJ(0, 2) CASE_IJ(0, 3) CASE_IJ(0, 4)
        CASE_IJ(1, 0) CASE_IJ(1, 1) CASE_IJ(1, 2) CASE_IJ(1, 3) CASE_IJ(1, 4)
        CASE_IJ(2, 0) CASE_IJ(2, 1) CASE_IJ(2, 2) CASE_IJ(2, 3) CASE_IJ(2, 4)
        CASE_IJ(3, 0) CASE_IJ(3, 1) CASE_IJ(3, 2) CASE_IJ(3, 3) CASE_IJ(3, 4)
        CASE_IJ(4, 0) CASE_IJ(4, 1) CASE_IJ(4, 2) CASE_IJ(4, 3) CASE_IJ(4, 4)
#undef CASE_IJ
#undef TERM
        default: s0 = 0.0f; s1 = 0.0f; break;
        }

        *outp = make_float2(s0, s1);    // 8B/lane coalesced store
        outp += DIM / 2;
    }
}

extern "C" void kernel_launch(void* const* d_in, const int* in_sizes, int n_in,
                              void* d_out, int out_size, void* d_ws, size_t ws_size,
                              hipStream_t stream) {
    const float* xy = (const float*)d_in[0];
    const float* Tx = (const float*)d_in[1];
    const float* Ty = (const float*)d_in[2];
    const float* C  = (const float*)d_in[3];
    float* out = (float*)d_out;

    int*   offs = (int*)d_ws;                    // 32768 ints
    float* wts  = (float*)d_ws + NPTS;           // 32768 x 12 floats

    precompute_kernel<<<NPTS / 256, 256, 0, stream>>>(xy, Tx, Ty, offs, wts);
    spline_main_kernel<<<2 * (NPTS / PPB), 256, 0, stream>>>(C, offs, wts, out);
}

// Round 5
// 38.431 us; speedup vs baseline: 5.4393x; 1.1788x over previous
//
#include <hip/hip_runtime.h>

// SplineConv: out[n, o, i] = sum_{a,b in 0..2} wx[n,a]*wy[n,b] * C[o,i,kx-2+a,ky-2+b]
// N=32768 points, C is (32,32,7,7) f32, out is (N,32,32) f32 = 128 MiB (HBM-write-bound).
//
// Round-5 structure: SINGLE kernel. Each block owns (64-point chunk) x (512-channel
// half). First 64 threads compute the 64 point-records (9 collapsed weights + window
// offset) straight into LDS; one barrier; main loop reads records from LDS (uniform
// address -> broadcast, lgkmcnt pipe, prefetched one point ahead). Each thread owns
// TWO channels, planar c[98] in registers, compile-time indices only. Window offset
// is READFIRSTLANE'd so the 25-way switch is a scalar jump table (vector switch
// gets if-converted to ~500 predicated VALU ops/point - round-1 lesson).

#define NPTS   32768
#define DIM    1024        // 32*32 channels
#define PPB    64          // points per block
#define RSTR   12          // floats per LDS record (48B: 16B-aligned for ds_read_b128)

__device__ __forceinline__ float safe_div(float n, float d) {
    return (d == 0.0f) ? n : (n / d);
}

__device__ __forceinline__ void span_weights(float v, const float* __restrict__ T,
                                             int& k, float& w0, float& w1, float& w2) {
    float t3 = T[3], t4 = T[4], t5 = T[5], t6 = T[6];
    k = 2 + (v >= t3) + (v >= t4) + (v >= t5) + (v >= t6);
    float Tm1 = T[k - 1], T0 = T[k], Tp1 = T[k + 1], Tp2 = T[k + 2];
    float a10 = safe_div(v - Tm1, Tp1 - Tm1);
    float a11 = safe_div(v - T0,  Tp2 - T0);
    float a21 = safe_div(v - T0,  Tp1 - T0);
    w0 = (1.0f - a21) * (1.0f - a10);
    w1 = (1.0f - a21) * a10 + a21 * (1.0f - a11);
    w2 = a21 * a11;
}

__global__ __launch_bounds__(256) void spline_main_kernel(
    const float* __restrict__ C,
    const float* __restrict__ xy,
    const float* __restrict__ Tx,
    const float* __restrict__ Ty,
    float* __restrict__ out)
{
    __shared__ float recs[PPB][RSTR];

    const int t     = threadIdx.x;
    const int g     = blockIdx.x & 1;          // channel half: 0 or 1
    const int chunk = blockIdx.x >> 1;
    const int p0    = chunk * PPB;
    const int ch    = g * 512 + t * 2;         // this thread's first channel

    // --- Wave 0: compute this block's 64 point-records into LDS -------------
    if (t < PPB) {
        const int p = p0 + t;
        const float2 pt = ((const float2*)xy)[p];
        int kx, ky;
        float wx0, wx1, wx2, wy0, wy1, wy2;
        span_weights(pt.x, Tx, kx, wx0, wx1, wx2);
        span_weights(pt.y, Ty, ky, wy0, wy1, wy2);
        float* r = recs[t];
        r[0] = wx0 * wy0;  r[1] = wx0 * wy1;  r[2] = wx0 * wy2;
        r[3] = wx1 * wy0;  r[4] = wx1 * wy1;  r[5] = wx1 * wy2;
        r[6] = wx2 * wy0;  r[7] = wx2 * wy1;  r[8] = wx2 * wy2;
        r[9] = __int_as_float((kx - 2) * 7 + (ky - 2));
        r[10] = 0.0f; r[11] = 0.0f;
    }

    // --- All threads: two channel rows -> registers, PLANAR ------------------
    // c[0..48] = C row ch, c[49..97] = C row ch+1 (ch even -> 8B-aligned).
    float c[98];
    {
        const float2* src = (const float2*)(C + (size_t)ch * 49);
#pragma unroll
        for (int q = 0; q < 49; ++q) {
            float2 v = src[q];
            c[2 * q]     = v.x;     // linear fill: c[i] = C[ch*49 + i]
            c[2 * q + 1] = v.y;
        }
    }

    __syncthreads();

    float2* outp = (float2*)(out + (size_t)p0 * DIM + ch);

    // Prefetch first record from LDS (uniform address -> broadcast).
    float4 wA = *(const float4*)(&recs[0][0]);
    float4 wB = *(const float4*)(&recs[0][4]);
    float2 wC = *(const float2*)(&recs[0][8]);

    for (int i = 0; i < PPB; ++i) {
        const float w0 = wA.x, w1 = wA.y, w2 = wA.z, w3 = wA.w;
        const float w4 = wB.x, w5 = wB.y, w6 = wB.z, w7 = wB.w;
        const float w8 = wC.x;
        const int off = __builtin_amdgcn_readfirstlane(__float_as_int(wC.y));

        if (i + 1 < PPB) {   // prefetch next record under this point's FMAs
            wA = *(const float4*)(&recs[i + 1][0]);
            wB = *(const float4*)(&recs[i + 1][4]);
            wC = *(const float2*)(&recs[i + 1][8]);
        }

        float s0, s1;
        switch (off) {
#define TERM(q, dq, w)                                      \
            s0 = fmaf(w, c[(q) + (dq)],      s0);           \
            s1 = fmaf(w, c[49 + (q) + (dq)], s1);
#define CASE_IJ(i_, j_)                                     \
        case ((i_) * 7 + (j_)): {                           \
            const int q = (i_) * 7 + (j_);                  \
            s0 = w0 * c[q];                                 \
            s1 = w0 * c[49 + q];                            \
            TERM(q, 1,  w1)  TERM(q, 2,  w2)                \
            TERM(q, 7,  w3)  TERM(q, 8,  w4)  TERM(q, 9,  w5) \
            TERM(q, 14, w6)  TERM(q, 15, w7)  TERM(q, 16, w8) \
        } break;
        CASE_IJ(0, 0) CASE_IJ(0, 1) CASE_IJ(0, 2) CASE_IJ(0, 3) CASE_IJ(0, 4)
        CASE_IJ(1, 0) CASE_IJ(1, 1) CASE_IJ(1, 2) CASE_IJ(1, 3) CASE_IJ(1, 4)
        CASE_IJ(2, 0) CASE_IJ(2, 1) CASE_IJ(2, 2) CASE_IJ(2, 3) CASE_IJ(2, 4)
        CASE_IJ(3, 0) CASE_IJ(3, 1) CASE_IJ(3, 2) CASE_IJ(3, 3) CASE_IJ(3, 4)
        CASE_IJ(4, 0) CASE_IJ(4, 1) CASE_IJ(4, 2) CASE_IJ(4, 3) CASE_IJ(4, 4)
#undef CASE_IJ
#undef TERM
        default: s0 = 0.0f; s1 = 0.0f; break;
        }

        *outp = make_float2(s0, s1);    // 8B/lane coalesced store
        outp += DIM / 2;
    }
}

extern "C" void kernel_launch(void* const* d_in, const int* in_sizes, int n_in,
                              void* d_out, int out_size, void* d_ws, size_t ws_size,
                              hipStream_t stream) {
    const float* xy = (const float*)d_in[0];
    const float* Tx = (const float*)d_in[1];
    const float* Ty = (const float*)d_in[2];
    const float* C  = (const float*)d_in[3];
    float* out = (float*)d_out;

    spline_main_kernel<<<2 * (NPTS / PPB), 256, 0, stream>>>(C, xy, Tx, Ty, out);
}